// Round 3
// baseline (212.845 us; speedup 1.0000x reference)
//
#include <hip/hip_runtime.h>
#include <hip/hip_bf16.h>
#include <math.h>

typedef __attribute__((ext_vector_type(8))) short short8;
typedef __attribute__((ext_vector_type(4))) float f32x4;
typedef __attribute__((ext_vector_type(4))) float float4v;
typedef __attribute__((ext_vector_type(4))) unsigned short ushort4v;

#define B_ 4
#define S_ 4096
#define D_ 128

// split-KV geometry: q-tile = 64 rows, kv-tile = 64 rows, chunk = 8 kv-tiles (512 keys)
#define CHUNKS_PER_BATCH 288
#define NSLOT (B_ * CHUNKS_PER_BATCH)   // 1152 partial slots

__device__ __forceinline__ unsigned short f2bf(float f) {
    union { float f; unsigned u; } v; v.f = f;
    unsigned r = v.u + 0x7FFFu + ((v.u >> 16) & 1u);
    return (unsigned short)(r >> 16);
}
__device__ __forceinline__ float bf2f(unsigned short h) {
    union { unsigned u; float f; } v; v.u = ((unsigned)h) << 16;
    return v.f;
}

// ---------------- kernel 0: W -> bf16, concat [Wq;Wk;Wv] as [384][128] ----------------
__global__ void wconv_kernel(const float* __restrict__ Wq,
                             const float* __restrict__ Wk,
                             const float* __restrict__ Wv,
                             unsigned short* __restrict__ Wb) {
    int i = blockIdx.x * 256 + threadIdx.x;
    if (i >= 3 * 16384) return;
    const float* s = (i < 16384) ? Wq : (i < 32768 ? Wk : Wv);
    Wb[i] = f2bf(s[i & 16383]);
}

// ---------------- kernel 1: QKV projection, no LDS, no barriers ----------------
// grid (256, 3): x = 64-row tile, y = weight group (0=Q,1=K,2=V)
__global__ __launch_bounds__(256) void qkv_kernel(const float* __restrict__ X,
                                                  const unsigned short* __restrict__ Wb,
                                                  unsigned short* __restrict__ Qb,
                                                  unsigned short* __restrict__ Kb,
                                                  unsigned short* __restrict__ Vt) {
    const int tid = threadIdx.x;
    const int lane = tid & 63, w = tid >> 6;
    const int l16 = lane & 15, g = lane >> 4;
    const int r0 = blockIdx.x * 64;
    const int grp = blockIdx.y;

    // A-fragments straight from global: row = r0 + w*16 + l16, k = kb*32 + g*8 + j
    const int row = r0 + w * 16 + l16;
    const float* xr = X + (long)row * 128;
    float4v x0[4], x1[4];
    #pragma unroll
    for (int kb = 0; kb < 4; ++kb) {
        x0[kb] = *reinterpret_cast<const float4v*>(xr + kb * 32 + g * 8);
        x1[kb] = *reinterpret_cast<const float4v*>(xr + kb * 32 + g * 8 + 4);
    }
    short8 a[4];
    #pragma unroll
    for (int kb = 0; kb < 4; ++kb) {
        short8 t;
        t[0] = f2bf(x0[kb][0]); t[1] = f2bf(x0[kb][1]);
        t[2] = f2bf(x0[kb][2]); t[3] = f2bf(x0[kb][3]);
        t[4] = f2bf(x1[kb][0]); t[5] = f2bf(x1[kb][1]);
        t[6] = f2bf(x1[kb][2]); t[7] = f2bf(x1[kb][3]);
        a[kb] = t;
    }

    #pragma unroll
    for (int ct = 0; ct < 8; ++ct) {
        const int e = ct * 16 + l16;          // column within group, 0..127
        const int c = grp * 128 + e;          // row of concatenated W
        f32x4 acc = {0.f, 0.f, 0.f, 0.f};
        #pragma unroll
        for (int kb = 0; kb < 4; ++kb) {
            short8 bf = *reinterpret_cast<const short8*>(Wb + (long)c * 128 + kb * 32 + g * 8);
            acc = __builtin_amdgcn_mfma_f32_16x16x32_bf16(a[kb], bf, acc, 0, 0, 0);
        }
        const int row0 = r0 + w * 16 + g * 4;
        if (grp == 0) {
            #pragma unroll
            for (int r = 0; r < 4; ++r) Qb[(long)(row0 + r) * 128 + e] = f2bf(acc[r]);
        } else if (grp == 1) {
            #pragma unroll
            for (int r = 0; r < 4; ++r) Kb[(long)(row0 + r) * 128 + e] = f2bf(acc[r]);
        } else {
            const int bb = row0 >> 12, ss = row0 & 4095;
            ushort4v p;
            p[0] = f2bf(acc[0]); p[1] = f2bf(acc[1]); p[2] = f2bf(acc[2]); p[3] = f2bf(acc[3]);
            *reinterpret_cast<ushort4v*>(&Vt[((long)bb * 128 + e) * 4096 + ss]) = p;
        }
    }
}

// ---------------- kernel 2: split-KV flash attention (causal), reg-prefetch pipeline ----------------
__global__ __launch_bounds__(256, 3) void attn_kernel(const unsigned short* __restrict__ Qb,
                                                      const unsigned short* __restrict__ Kb,
                                                      const unsigned short* __restrict__ Vt,
                                                      unsigned short* __restrict__ Opart,
                                                      float* __restrict__ Mpart,
                                                      float* __restrict__ Lpart) {
    __shared__ __align__(16) unsigned char lds[40960];

    const int tid = threadIdx.x;
    const int lane = tid & 63, w = tid >> 6;
    const int l16 = lane & 15, g = lane >> 4;

    // block -> (b, qt, c)
    const int bidx = (int)blockIdx.x;
    const int b = bidx / CHUNKS_PER_BATCH;
    const int rr = bidx - b * CHUNKS_PER_BATCH;
    int gg = 0;
    while (4 * (gg + 1) * (gg + 2) <= rr) ++gg;
    const int j = rr - 4 * gg * (gg + 1);
    const int qt = 8 * gg + j / (gg + 1);
    const int c = j % (gg + 1);
    const int slot = bidx;

    const unsigned short* Qbase = Qb + (long)b * S_ * D_;
    const unsigned short* Kbase = Kb + (long)b * S_ * D_;
    const unsigned short* Vbase = Vt + (long)b * D_ * S_;

    const int qrow_f = qt * 64 + w * 16 + l16;
    short8 qf[4];
    #pragma unroll
    for (int kb = 0; kb < 4; ++kb)
        qf[kb] = *reinterpret_cast<const short8*>(Qbase + (long)qrow_f * 128 + kb * 32 + g * 8);

    f32x4 o[8];
    #pragma unroll
    for (int dt = 0; dt < 8; ++dt) o[dt] = (f32x4){0.f, 0.f, 0.f, 0.f};
    float m[4], lsum[4];
    int myrow[4];
    #pragma unroll
    for (int r = 0; r < 4; ++r) {
        m[r] = -INFINITY; lsum[r] = 0.f;
        myrow[r] = qt * 64 + w * 16 + g * 4 + r;
    }

    const float scale = 0.08838834764831845f; // 1/sqrt(128)
    const int kt0 = c * 8;
    const int ktend = min(kt0 + 7, qt);

    // staging registers + addresses (per-thread fixed within-tile offsets)
    const int kch = tid, krow0 = kch >> 2, kcd = kch & 3;          // wrong split; fix below
    (void)kch; (void)krow0; (void)kcd;

    short8 kR[4], vR[4];
    int kbyt[4], vbyt[4];
    const unsigned short* kaddr[4];
    const unsigned short* vaddr[4];
    #pragma unroll
    for (int it = 0; it < 4; ++it) {
        int ch = it * 256 + tid;
        int row = ch >> 4, cd = ch & 15;               // K tile [64][128]
        kaddr[it] = Kbase + (long)row * 128 + cd * 8;  // + kt*64*128 at use
        kbyt[it] = (row * 256 + cd * 16) ^ ((row & 7) << 4);
        int rowd = ch >> 3, ckv = ch & 7;              // V tile [128][64]
        vaddr[it] = Vbase + (long)rowd * 4096 + ckv * 8;  // + kt*64 at use
        vbyt[it] = 16384 + ((rowd * 128 + ckv * 16) ^ ((rowd & 7) << 4));
    }

    // prologue: load tile kt0, write to LDS
    #pragma unroll
    for (int it = 0; it < 4; ++it) {
        kR[it] = *reinterpret_cast<const short8*>(kaddr[it] + (long)kt0 * 64 * 128);
        vR[it] = *reinterpret_cast<const short8*>(vaddr[it] + kt0 * 64);
    }
    #pragma unroll
    for (int it = 0; it < 4; ++it) {
        *reinterpret_cast<short8*>(lds + kbyt[it]) = kR[it];
        *reinterpret_cast<short8*>(lds + vbyt[it]) = vR[it];
    }
    __syncthreads();

    for (int kt = kt0; kt <= ktend; ++kt) {
        const bool more = (kt < ktend);
        // issue next tile's loads early — latency hides under compute below
        if (more) {
            #pragma unroll
            for (int it = 0; it < 4; ++it) {
                kR[it] = *reinterpret_cast<const short8*>(kaddr[it] + (long)(kt + 1) * 64 * 128);
                vR[it] = *reinterpret_cast<const short8*>(vaddr[it] + (kt + 1) * 64);
            }
        }

        // ---- S = Q K^T ----
        f32x4 s[4];
        #pragma unroll
        for (int ct = 0; ct < 4; ++ct) {
            s[ct] = (f32x4){0.f, 0.f, 0.f, 0.f};
            const int kvl = ct * 16 + l16;
            #pragma unroll
            for (int kb = 0; kb < 4; ++kb) {
                int byt = (kvl * 256 + kb * 64 + g * 16) ^ ((kvl & 7) << 4);
                short8 kf = *reinterpret_cast<const short8*>(lds + byt);
                s[ct] = __builtin_amdgcn_mfma_f32_16x16x32_bf16(qf[kb], kf, s[ct], 0, 0, 0);
            }
        }

        // ---- online softmax ----
        const bool diag = (kt == qt);
        float rmax[4] = {-1e30f, -1e30f, -1e30f, -1e30f};
        #pragma unroll
        for (int ct = 0; ct < 4; ++ct) {
            #pragma unroll
            for (int r = 0; r < 4; ++r) {
                float sv = s[ct][r] * scale;
                if (diag && (kt * 64 + ct * 16 + l16 > myrow[r])) sv = -1e30f;
                s[ct][r] = sv;
                rmax[r] = fmaxf(rmax[r], sv);
            }
        }
        #pragma unroll
        for (int off = 1; off < 16; off <<= 1) {
            #pragma unroll
            for (int r = 0; r < 4; ++r) rmax[r] = fmaxf(rmax[r], __shfl_xor(rmax[r], off, 64));
        }
        float al[4], rsum[4];
        #pragma unroll
        for (int r = 0; r < 4; ++r) {
            float mn = fmaxf(m[r], rmax[r]);
            al[r] = __expf(m[r] - mn);
            m[r] = mn;
            rsum[r] = 0.f;
        }
        #pragma unroll
        for (int ct = 0; ct < 4; ++ct) {
            #pragma unroll
            for (int r = 0; r < 4; ++r) {
                float p = __expf(s[ct][r] - m[r]);
                s[ct][r] = p;
                rsum[r] += p;
            }
        }
        #pragma unroll
        for (int off = 1; off < 16; off <<= 1) {
            #pragma unroll
            for (int r = 0; r < 4; ++r) rsum[r] += __shfl_xor(rsum[r], off, 64);
        }
        #pragma unroll
        for (int r = 0; r < 4; ++r) lsum[r] = lsum[r] * al[r] + rsum[r];
        #pragma unroll
        for (int dt = 0; dt < 8; ++dt) {
            #pragma unroll
            for (int r = 0; r < 4; ++r) o[dt][r] *= al[r];
        }

        // ---- P -> per-wave LDS (swizzled) ----
        unsigned char* Pw = lds + 32768 + w * 2048;
        #pragma unroll
        for (int ct = 0; ct < 4; ++ct) {
            #pragma unroll
            for (int r = 0; r < 4; ++r) {
                int pr = g * 4 + r, pc = ct * 16 + l16;
                int byt = (pr * 128 + pc * 2) ^ ((pr & 7) << 4);
                *reinterpret_cast<unsigned short*>(Pw + byt) = f2bf(s[ct][r]);
            }
        }

        // ---- O += P V ----
        #pragma unroll
        for (int kvb = 0; kvb < 2; ++kvb) {
            int pbyt = (l16 * 128 + kvb * 64 + g * 16) ^ ((l16 & 7) << 4);
            short8 pf = *reinterpret_cast<const short8*>(Pw + pbyt);
            #pragma unroll
            for (int dt = 0; dt < 8; ++dt) {
                int d = dt * 16 + l16;
                int vbyt2 = 16384 + ((d * 128 + kvb * 64 + g * 16) ^ ((d & 7) << 4));
                short8 vf = *reinterpret_cast<const short8*>(lds + vbyt2);
                o[dt] = __builtin_amdgcn_mfma_f32_16x16x32_bf16(pf, vf, o[dt], 0, 0, 0);
            }
        }

        if (more) {
            __syncthreads();   // everyone done reading current tile
            #pragma unroll
            for (int it = 0; it < 4; ++it) {
                *reinterpret_cast<short8*>(lds + kbyt[it]) = kR[it];
                *reinterpret_cast<short8*>(lds + vbyt[it]) = vR[it];
            }
            __syncthreads();   // next tile ready
        }
    }

    // ---- partial epilogue: unnormalized O (bf16) + m,l (f32) ----
    unsigned short* Op = Opart + (long)slot * 8192;
    #pragma unroll
    for (int dt = 0; dt < 8; ++dt) {
        #pragma unroll
        for (int r = 0; r < 4; ++r) {
            Op[(w * 16 + g * 4 + r) * 128 + dt * 16 + l16] = f2bf(o[dt][r]);
        }
    }
    if (l16 == 0) {
        #pragma unroll
        for (int r = 0; r < 4; ++r) {
            Mpart[(long)slot * 64 + w * 16 + g * 4 + r] = m[r];
            Lpart[(long)slot * 64 + w * 16 + g * 4 + r] = lsum[r];
        }
    }
}

// ---------------- kernel 3: combine partials ----------------
// grid (256, 4): x = qt*4 + quarter, y = b. Each block merges 16 rows of one q-tile.
__global__ __launch_bounds__(256) void combine_kernel(const unsigned short* __restrict__ Opart,
                                                      const float* __restrict__ Mpart,
                                                      const float* __restrict__ Lpart,
                                                      float* __restrict__ out) {
    __shared__ float coeff[8][16];
    __shared__ float invL[16];

    const int qt = blockIdx.x >> 2, qq = blockIdx.x & 3, b = blockIdx.y;
    const int gg = qt >> 3;
    const int nc = gg + 1;
    const int slot0 = b * CHUNKS_PER_BATCH + 4 * gg * (gg + 1) + (qt - 8 * gg) * nc;
    const int r0 = qq * 16;   // local row within the 64-row tile

    const int tid = threadIdx.x;
    if (tid < 16) {
        float mg = -INFINITY;
        for (int c = 0; c < nc; ++c)
            mg = fmaxf(mg, Mpart[(long)(slot0 + c) * 64 + r0 + tid]);
        float L = 0.f;
        for (int c = 0; c < nc; ++c) {
            float co = __expf(Mpart[(long)(slot0 + c) * 64 + r0 + tid] - mg);
            coeff[c][tid] = co;
            L += co * Lpart[(long)(slot0 + c) * 64 + r0 + tid];
        }
        invL[tid] = 1.f / L;
    }
    __syncthreads();

    // 16 rows x 128 cols = 2048 elems, 8 per thread
    const int e0 = tid * 8;
    const int r = e0 >> 7;
    float acc[8];
    #pragma unroll
    for (int k = 0; k < 8; ++k) acc[k] = 0.f;
    for (int c = 0; c < nc; ++c) {
        short8 v = *reinterpret_cast<const short8*>(Opart + (long)(slot0 + c) * 8192 + r0 * 128 + e0);
        const float co = coeff[c][r];
        #pragma unroll
        for (int k = 0; k < 8; ++k)
            acc[k] += co * bf2f((unsigned short)v[k]);
    }
    const float s = invL[r];
    float4v o0, o1;
    o0[0] = acc[0] * s; o0[1] = acc[1] * s; o0[2] = acc[2] * s; o0[3] = acc[3] * s;
    o1[0] = acc[4] * s; o1[1] = acc[5] * s; o1[2] = acc[6] * s; o1[3] = acc[7] * s;
    float* dst = out + ((long)b * S_ + qt * 64 + r0) * 128 + e0;
    *reinterpret_cast<float4v*>(dst) = o0;
    *reinterpret_cast<float4v*>(dst + 4) = o1;
}

extern "C" void kernel_launch(void* const* d_in, const int* in_sizes, int n_in,
                              void* d_out, int out_size, void* d_ws, size_t ws_size,
                              hipStream_t stream) {
    (void)in_sizes; (void)n_in; (void)out_size; (void)ws_size;
    const float* x  = (const float*)d_in[0];
    const float* Wq = (const float*)d_in[1];
    const float* Wk = (const float*)d_in[2];
    const float* Wv = (const float*)d_in[3];
    float* out = (float*)d_out;

    char* ws = (char*)d_ws;
    const size_t MB4 = (size_t)16384 * 128 * 2;         // 4 MiB per bf16 tensor
    unsigned short* Qb = (unsigned short*)(ws);
    unsigned short* Kb = (unsigned short*)(ws + MB4);
    unsigned short* Vt = (unsigned short*)(ws + 2 * MB4);
    unsigned short* Wb = (unsigned short*)(ws + 3 * MB4);          // 96 KiB
    unsigned short* Opart = (unsigned short*)(ws + 3 * MB4 + (1 << 20));   // 1152*16KiB
    float* Mpart = (float*)(ws + 3 * MB4 + (1 << 20) + (size_t)NSLOT * 8192 * 2);
    float* Lpart = Mpart + (size_t)NSLOT * 64;

    wconv_kernel<<<192, 256, 0, stream>>>(Wq, Wk, Wv, Wb);
    qkv_kernel<<<dim3(256, 3), 256, 0, stream>>>(x, Wb, Qb, Kb, Vt);
    attn_kernel<<<NSLOT, 256, 0, stream>>>(Qb, Kb, Vt, Opart, Mpart, Lpart);
    combine_kernel<<<dim3(256, 4), 256, 0, stream>>>(Opart, Mpart, Lpart, out);
}

// Round 4
// 152.890 us; speedup vs baseline: 1.3921x; 1.3921x over previous
//
#include <hip/hip_runtime.h>
#include <hip/hip_bf16.h>
#include <math.h>

typedef __attribute__((ext_vector_type(8))) short short8;
typedef __attribute__((ext_vector_type(4))) float f32x4;
typedef __attribute__((ext_vector_type(4))) float float4v;
typedef __attribute__((ext_vector_type(4))) unsigned short ushort4v;

typedef __attribute__((address_space(1))) const unsigned int GAS;
typedef __attribute__((address_space(3))) unsigned int LAS;

#define B_ 4
#define S_ 4096
#define D_ 128

// split-KV geometry: q-tile = 64 rows, kv-tile = 64 rows, chunk = 8 kv-tiles (512 keys)
#define CHUNKS_PER_BATCH 288
#define NSLOT (B_ * CHUNKS_PER_BATCH)   // 1152 partial slots

// LDS layout (bytes): K tile 16K | V tile double-buffered 2x16K | P per-wave 4x2K
#define LDS_K 0
#define LDS_V 16384
#define LDS_P 49152
#define LDS_TOTAL 57344

__device__ __forceinline__ unsigned short f2bf(float f) {
    union { float f; unsigned u; } v; v.f = f;
    unsigned r = v.u + 0x7FFFu + ((v.u >> 16) & 1u);
    return (unsigned short)(r >> 16);
}
__device__ __forceinline__ float bf2f(unsigned short h) {
    union { unsigned u; float f; } v; v.u = ((unsigned)h) << 16;
    return v.f;
}

// ---------------- kernel 0: W -> bf16, concat [Wq;Wk;Wv] as [384][128] ----------------
__global__ void wconv_kernel(const float* __restrict__ Wq,
                             const float* __restrict__ Wk,
                             const float* __restrict__ Wv,
                             unsigned short* __restrict__ Wb) {
    int i = blockIdx.x * 256 + threadIdx.x;
    if (i >= 3 * 16384) return;
    const float* s = (i < 16384) ? Wq : (i < 32768 ? Wk : Wv);
    Wb[i] = f2bf(s[i & 16383]);
}

// ---------------- kernel 1: QKV projection, no LDS, no barriers ----------------
// grid (256, 3): x = 64-row tile, y = weight group (0=Q,1=K,2=V)
__global__ __launch_bounds__(256) void qkv_kernel(const float* __restrict__ X,
                                                  const unsigned short* __restrict__ Wb,
                                                  unsigned short* __restrict__ Qb,
                                                  unsigned short* __restrict__ Kb,
                                                  unsigned short* __restrict__ Vt) {
    const int tid = threadIdx.x;
    const int lane = tid & 63, w = tid >> 6;
    const int l16 = lane & 15, g = lane >> 4;
    const int r0 = blockIdx.x * 64;
    const int grp = blockIdx.y;

    const int row = r0 + w * 16 + l16;
    const float* xr = X + (long)row * 128;
    float4v x0[4], x1[4];
    #pragma unroll
    for (int kb = 0; kb < 4; ++kb) {
        x0[kb] = *reinterpret_cast<const float4v*>(xr + kb * 32 + g * 8);
        x1[kb] = *reinterpret_cast<const float4v*>(xr + kb * 32 + g * 8 + 4);
    }
    short8 a[4];
    #pragma unroll
    for (int kb = 0; kb < 4; ++kb) {
        short8 t;
        t[0] = f2bf(x0[kb][0]); t[1] = f2bf(x0[kb][1]);
        t[2] = f2bf(x0[kb][2]); t[3] = f2bf(x0[kb][3]);
        t[4] = f2bf(x1[kb][0]); t[5] = f2bf(x1[kb][1]);
        t[6] = f2bf(x1[kb][2]); t[7] = f2bf(x1[kb][3]);
        a[kb] = t;
    }

    #pragma unroll
    for (int ct = 0; ct < 8; ++ct) {
        const int e = ct * 16 + l16;
        const int c = grp * 128 + e;
        f32x4 acc = {0.f, 0.f, 0.f, 0.f};
        #pragma unroll
        for (int kb = 0; kb < 4; ++kb) {
            short8 bf = *reinterpret_cast<const short8*>(Wb + (long)c * 128 + kb * 32 + g * 8);
            acc = __builtin_amdgcn_mfma_f32_16x16x32_bf16(a[kb], bf, acc, 0, 0, 0);
        }
        const int row0 = r0 + w * 16 + g * 4;
        if (grp == 0) {
            #pragma unroll
            for (int r = 0; r < 4; ++r) Qb[(long)(row0 + r) * 128 + e] = f2bf(acc[r]);
        } else if (grp == 1) {
            #pragma unroll
            for (int r = 0; r < 4; ++r) Kb[(long)(row0 + r) * 128 + e] = f2bf(acc[r]);
        } else {
            const int bb = row0 >> 12, ss = row0 & 4095;
            ushort4v p;
            p[0] = f2bf(acc[0]); p[1] = f2bf(acc[1]); p[2] = f2bf(acc[2]); p[3] = f2bf(acc[3]);
            *reinterpret_cast<ushort4v*>(&Vt[((long)bb * 128 + e) * 4096 + ss]) = p;
        }
    }
}

// ---------------- kernel 2: split-KV flash attention, global_load_lds pipeline ----------------
__global__ __launch_bounds__(256) void attn_kernel(const unsigned short* __restrict__ Qb,
                                                   const unsigned short* __restrict__ Kb,
                                                   const unsigned short* __restrict__ Vt,
                                                   unsigned short* __restrict__ Opart,
                                                   float* __restrict__ Mpart,
                                                   float* __restrict__ Lpart) {
    __shared__ __align__(16) unsigned char lds[LDS_TOTAL];

    const int tid = threadIdx.x;
    const int lane = tid & 63, w = tid >> 6;
    const int l16 = lane & 15, g = lane >> 4;

    // block -> (b, qt, c)
    const int bidx = (int)blockIdx.x;
    const int b = bidx / CHUNKS_PER_BATCH;
    const int rr = bidx - b * CHUNKS_PER_BATCH;
    int gg = 0;
    while (4 * (gg + 1) * (gg + 2) <= rr) ++gg;
    const int j = rr - 4 * gg * (gg + 1);
    const int qt = 8 * gg + j / (gg + 1);
    const int c = j % (gg + 1);
    const int slot = bidx;

    const unsigned short* Qbase = Qb + (long)b * S_ * D_;
    const unsigned char* Kb_b = (const unsigned char*)(Kb + (long)b * S_ * D_);
    const unsigned char* Vb_b = (const unsigned char*)(Vt + (long)b * D_ * S_);

    // Q fragments
    const int qrow_f = qt * 64 + w * 16 + l16;
    short8 qf[4];
    #pragma unroll
    for (int kb = 0; kb < 4; ++kb)
        qf[kb] = *reinterpret_cast<const short8*>(Qbase + (long)qrow_f * 128 + kb * 32 + g * 8);

    // pre-swizzled global source offsets for DMA staging (involution XOR)
    // K: chunk ch = w*4+i covers rows ch*4..ch*4+3 (256B rows); lane writes LDS at row*256 + l16*16
    // V: chunk ch covers rows ch*8..ch*8+7 (128B rows); lane writes LDS at row*128 + (l&7)*16
    int koff[4], voff[4];
    #pragma unroll
    for (int i = 0; i < 4; ++i) {
        int ch = w * 4 + i;
        int krow = ch * 4 + g;
        koff[i] = krow * 256 + ((l16 * 16) ^ ((krow & 7) << 4));
        int vrow = ch * 8 + (lane >> 3);
        voff[i] = vrow * 8192 + (((lane & 7) * 16) ^ ((vrow & 7) << 4));
    }

    f32x4 o[8];
    #pragma unroll
    for (int dt = 0; dt < 8; ++dt) o[dt] = (f32x4){0.f, 0.f, 0.f, 0.f};
    float m[4], lsum[4];
    int myrow[4];
    #pragma unroll
    for (int r = 0; r < 4; ++r) {
        m[r] = -INFINITY; lsum[r] = 0.f;
        myrow[r] = qt * 64 + w * 16 + g * 4 + r;
    }

    const float scale = 0.08838834764831845f; // 1/sqrt(128)
    const int kt0 = c * 8;
    const int ktend = min(kt0 + 7, qt);

    // prologue: DMA tile kt0
    #pragma unroll
    for (int i = 0; i < 4; ++i) {
        int ch = w * 4 + i;
        __builtin_amdgcn_global_load_lds((GAS*)(Kb_b + (long)kt0 * 16384 + koff[i]),
                                         (LAS*)(lds + LDS_K + ch * 1024), 16, 0, 0);
        __builtin_amdgcn_global_load_lds((GAS*)(Vb_b + (long)kt0 * 128 + voff[i]),
                                         (LAS*)(lds + LDS_V + (kt0 & 1) * 16384 + ch * 1024), 16, 0, 0);
    }
    __syncthreads();

    for (int kt = kt0; kt <= ktend; ++kt) {
        const int buf = kt & 1;
        const bool more = (kt < ktend);

        // ---- S = Q K^T ----
        f32x4 s[4];
        #pragma unroll
        for (int ct = 0; ct < 4; ++ct) {
            s[ct] = (f32x4){0.f, 0.f, 0.f, 0.f};
            const int kvl = ct * 16 + l16;
            #pragma unroll
            for (int kb = 0; kb < 4; ++kb) {
                int byt = (kvl * 256 + kb * 64 + g * 16) ^ ((kvl & 7) << 4);
                short8 kf = *reinterpret_cast<const short8*>(lds + byt);
                s[ct] = __builtin_amdgcn_mfma_f32_16x16x32_bf16(qf[kb], kf, s[ct], 0, 0, 0);
            }
        }

        __syncthreads();   // all waves done reading K tile

        // DMA next tile: K into the (single) K buffer, V into the other V buffer.
        // Latency hides under softmax + PV below; drained by the end-of-iter barrier.
        if (more) {
            #pragma unroll
            for (int i = 0; i < 4; ++i) {
                int ch = w * 4 + i;
                __builtin_amdgcn_global_load_lds((GAS*)(Kb_b + (long)(kt + 1) * 16384 + koff[i]),
                                                 (LAS*)(lds + LDS_K + ch * 1024), 16, 0, 0);
                __builtin_amdgcn_global_load_lds((GAS*)(Vb_b + (long)(kt + 1) * 128 + voff[i]),
                                                 (LAS*)(lds + LDS_V + (buf ^ 1) * 16384 + ch * 1024), 16, 0, 0);
            }
        }

        // ---- online softmax ----
        const bool diag = (kt == qt);
        float rmax[4] = {-1e30f, -1e30f, -1e30f, -1e30f};
        #pragma unroll
        for (int ct = 0; ct < 4; ++ct) {
            #pragma unroll
            for (int r = 0; r < 4; ++r) {
                float sv = s[ct][r] * scale;
                if (diag && (kt * 64 + ct * 16 + l16 > myrow[r])) sv = -1e30f;
                s[ct][r] = sv;
                rmax[r] = fmaxf(rmax[r], sv);
            }
        }
        #pragma unroll
        for (int off = 1; off < 16; off <<= 1) {
            #pragma unroll
            for (int r = 0; r < 4; ++r) rmax[r] = fmaxf(rmax[r], __shfl_xor(rmax[r], off, 64));
        }
        float al[4], rsum[4];
        #pragma unroll
        for (int r = 0; r < 4; ++r) {
            float mn = fmaxf(m[r], rmax[r]);
            al[r] = __expf(m[r] - mn);
            m[r] = mn;
            rsum[r] = 0.f;
        }
        #pragma unroll
        for (int ct = 0; ct < 4; ++ct) {
            #pragma unroll
            for (int r = 0; r < 4; ++r) {
                float p = __expf(s[ct][r] - m[r]);
                s[ct][r] = p;
                rsum[r] += p;
            }
        }
        #pragma unroll
        for (int off = 1; off < 16; off <<= 1) {
            #pragma unroll
            for (int r = 0; r < 4; ++r) rsum[r] += __shfl_xor(rsum[r], off, 64);
        }
        #pragma unroll
        for (int r = 0; r < 4; ++r) lsum[r] = lsum[r] * al[r] + rsum[r];
        #pragma unroll
        for (int dt = 0; dt < 8; ++dt) {
            #pragma unroll
            for (int r = 0; r < 4; ++r) o[dt][r] *= al[r];
        }

        // ---- P -> per-wave LDS (swizzled) ----
        unsigned char* Pw = lds + LDS_P + w * 2048;
        #pragma unroll
        for (int ct = 0; ct < 4; ++ct) {
            #pragma unroll
            for (int r = 0; r < 4; ++r) {
                int pr = g * 4 + r, pc = ct * 16 + l16;
                int byt = (pr * 128 + pc * 2) ^ ((pr & 7) << 4);
                *reinterpret_cast<unsigned short*>(Pw + byt) = f2bf(s[ct][r]);
            }
        }

        // ---- O += P V ----
        #pragma unroll
        for (int kvb = 0; kvb < 2; ++kvb) {
            int pbyt = (l16 * 128 + kvb * 64 + g * 16) ^ ((l16 & 7) << 4);
            short8 pf = *reinterpret_cast<const short8*>(Pw + pbyt);
            #pragma unroll
            for (int dt = 0; dt < 8; ++dt) {
                int d = dt * 16 + l16;
                int vbyt = LDS_V + buf * 16384 + ((d * 128 + kvb * 64 + g * 16) ^ ((d & 7) << 4));
                short8 vf = *reinterpret_cast<const short8*>(lds + vbyt);
                o[dt] = __builtin_amdgcn_mfma_f32_16x16x32_bf16(pf, vf, o[dt], 0, 0, 0);
            }
        }

        if (more) __syncthreads();   // drains DMA (vmcnt 0) + all waves done with tile
    }

    // ---- partial epilogue: unnormalized O (bf16) + m,l (f32) ----
    unsigned short* Op = Opart + (long)slot * 8192;
    #pragma unroll
    for (int dt = 0; dt < 8; ++dt) {
        #pragma unroll
        for (int r = 0; r < 4; ++r) {
            Op[(w * 16 + g * 4 + r) * 128 + dt * 16 + l16] = f2bf(o[dt][r]);
        }
    }
    if (l16 == 0) {
        #pragma unroll
        for (int r = 0; r < 4; ++r) {
            Mpart[(long)slot * 64 + w * 16 + g * 4 + r] = m[r];
            Lpart[(long)slot * 64 + w * 16 + g * 4 + r] = lsum[r];
        }
    }
}

// ---------------- kernel 3: combine partials ----------------
// grid (256, 4): x = qt*4 + quarter, y = b. Each block merges 16 rows of one q-tile.
__global__ __launch_bounds__(256) void combine_kernel(const unsigned short* __restrict__ Opart,
                                                      const float* __restrict__ Mpart,
                                                      const float* __restrict__ Lpart,
                                                      float* __restrict__ out) {
    __shared__ float coeff[8][16];
    __shared__ float invL[16];

    const int qt = blockIdx.x >> 2, qq = blockIdx.x & 3, b = blockIdx.y;
    const int gg = qt >> 3;
    const int nc = gg + 1;
    const int slot0 = b * CHUNKS_PER_BATCH + 4 * gg * (gg + 1) + (qt - 8 * gg) * nc;
    const int r0 = qq * 16;

    const int tid = threadIdx.x;
    if (tid < 16) {
        float mg = -INFINITY;
        for (int c = 0; c < nc; ++c)
            mg = fmaxf(mg, Mpart[(long)(slot0 + c) * 64 + r0 + tid]);
        float L = 0.f;
        for (int c = 0; c < nc; ++c) {
            float co = __expf(Mpart[(long)(slot0 + c) * 64 + r0 + tid] - mg);
            coeff[c][tid] = co;
            L += co * Lpart[(long)(slot0 + c) * 64 + r0 + tid];
        }
        invL[tid] = 1.f / L;
    }
    __syncthreads();

    const int e0 = tid * 8;
    const int r = e0 >> 7;
    float acc[8];
    #pragma unroll
    for (int k = 0; k < 8; ++k) acc[k] = 0.f;
    for (int c = 0; c < nc; ++c) {
        short8 v = *reinterpret_cast<const short8*>(Opart + (long)(slot0 + c) * 8192 + r0 * 128 + e0);
        const float co = coeff[c][r];
        #pragma unroll
        for (int k = 0; k < 8; ++k)
            acc[k] += co * bf2f((unsigned short)v[k]);
    }
    const float s = invL[r];
    float4v o0, o1;
    o0[0] = acc[0] * s; o0[1] = acc[1] * s; o0[2] = acc[2] * s; o0[3] = acc[3] * s;
    o1[0] = acc[4] * s; o1[1] = acc[5] * s; o1[2] = acc[6] * s; o1[3] = acc[7] * s;
    float* dst = out + ((long)b * S_ + qt * 64 + r0) * 128 + e0;
    *reinterpret_cast<float4v*>(dst) = o0;
    *reinterpret_cast<float4v*>(dst + 4) = o1;
}

extern "C" void kernel_launch(void* const* d_in, const int* in_sizes, int n_in,
                              void* d_out, int out_size, void* d_ws, size_t ws_size,
                              hipStream_t stream) {
    (void)in_sizes; (void)n_in; (void)out_size; (void)ws_size;
    const float* x  = (const float*)d_in[0];
    const float* Wq = (const float*)d_in[1];
    const float* Wk = (const float*)d_in[2];
    const float* Wv = (const float*)d_in[3];
    float* out = (float*)d_out;

    char* ws = (char*)d_ws;
    const size_t MB4 = (size_t)16384 * 128 * 2;         // 4 MiB per bf16 tensor
    unsigned short* Qb = (unsigned short*)(ws);
    unsigned short* Kb = (unsigned short*)(ws + MB4);
    unsigned short* Vt = (unsigned short*)(ws + 2 * MB4);
    unsigned short* Wb = (unsigned short*)(ws + 3 * MB4);          // 96 KiB
    unsigned short* Opart = (unsigned short*)(ws + 3 * MB4 + (1 << 20));
    float* Mpart = (float*)(ws + 3 * MB4 + (1 << 20) + (size_t)NSLOT * 8192 * 2);
    float* Lpart = Mpart + (size_t)NSLOT * 64;

    wconv_kernel<<<192, 256, 0, stream>>>(Wq, Wk, Wv, Wb);
    qkv_kernel<<<dim3(256, 3), 256, 0, stream>>>(x, Wb, Qb, Kb, Vt);
    attn_kernel<<<NSLOT, 256, 0, stream>>>(Qb, Kb, Vt, Opart, Mpart, Lpart);
    combine_kernel<<<dim3(256, 4), 256, 0, stream>>>(Opart, Mpart, Lpart, out);
}